// Round 2
// baseline (364.200 us; speedup 1.0000x reference)
//
#include <hip/hip_runtime.h>
#include <hip/hip_bf16.h>
#include <stdint.h>
#include <stddef.h>

// Causal single-head attention, B=4 S=2048 D=1024. fp32 in/out per reference;
// internal compute in bf16 MFMA (threshold is bf16-floored: 4.375e-2).
// Pipeline: downcast x,W* -> bf16 ; [Q;K] = x W^T (z=2) ; VT = Wv x^T ;
// Sc = Q K^T / 32 (bf16, causal tile skip) ; P = row-softmax(Sc) (bf16) ;
// out = P V (fp32 epilogue, K-loop clipped at diagonal).

typedef __hip_bfloat16 bf16;
typedef short short8 __attribute__((ext_vector_type(8)));
typedef short short4v __attribute__((ext_vector_type(4)));
typedef float f32x4 __attribute__((ext_vector_type(4)));

#define BM 128
#define BN 128
#define BK 32

__device__ __forceinline__ void async_ld16(void* lds, const void* g) {
  __builtin_amdgcn_global_load_lds(
      (const __attribute__((address_space(1))) unsigned int*)g,
      (__attribute__((address_space(3))) unsigned int*)lds, 16, 0, 0);
}

__device__ __forceinline__ void cstore(float* p, float v) { *p = v; }
__device__ __forceinline__ void cstore(bf16* p, float v) { *p = __float2bfloat16(v); }

// fp32 -> bf16 downcast, 4 elems/thread (16B load, 8B store)
__global__ __launch_bounds__(256)
void f2b(const float* __restrict__ s, bf16* __restrict__ d, int n) {
  const int i = (blockIdx.x * 256 + threadIdx.x) * 4;
  if (i >= n) return;
  const float4 v = *(const float4*)(s + i);
  bf16 t[4] = {__float2bfloat16(v.x), __float2bfloat16(v.y),
               __float2bfloat16(v.z), __float2bfloat16(v.w)};
  *(short4v*)(d + i) = *(short4v*)t;
}

// C[M,N] = A[M,K] * B[N,K]^T (both K-contiguous), bf16 inputs, CT output.
// m97 structure: global_load_lds width=16, k-chunk-swizzled LDS, 16x16x32 MFMA.
template <typename CT>
__global__ __launch_bounds__(256, 3)
void gemm_bt(const bf16* __restrict__ A, const bf16* __restrict__ B,
             CT* __restrict__ C, int lda, int ldb, int ldc, int K,
             long sA, long sB, long sC, float scale,
             int causal_skip, int causal_klimit) {
  if (causal_skip && blockIdx.x > blockIdx.y) return;  // tile fully above diagonal

  __shared__ short8 As[512];  // 8 KB: [q=0..3][m=0..127]
  __shared__ short8 Bs[512];  // 8 KB: [q=0..3][n=0..127]

  const int tid = threadIdx.x;
  const int wave = tid >> 6, lane = tid & 63;
  const int wm = wave >> 1, wn = wave & 1;  // 2x2 wave grid, 64x64 each
  const int l15 = lane & 15, q4 = lane >> 4;
  const int bm0 = blockIdx.y * BM, bn0 = blockIdx.x * BN;

  const bf16* Az = A + (long)blockIdx.z * sA;
  const bf16* Bz = B + (long)blockIdx.z * sB;
  CT* Cz = C + (long)blockIdx.z * sC;

  // wave w stages k-chunk q=w (cols k0+8w..+8) for rows {lane, lane+64}
  const bf16* ap0 = Az + (size_t)(bm0 + lane) * lda + wave * 8;
  const bf16* ap1 = ap0 + (size_t)64 * lda;
  const bf16* bp0 = Bz + (size_t)(bn0 + lane) * ldb + wave * 8;
  const bf16* bp1 = bp0 + (size_t)64 * ldb;
  short8* dstA0 = &As[wave * 128];
  short8* dstA1 = &As[wave * 128 + 64];
  short8* dstB0 = &Bs[wave * 128];
  short8* dstB1 = &Bs[wave * 128 + 64];

  const int Ke = causal_klimit ? min(K, (int)(blockIdx.y + 1) * BM) : K;

  f32x4 acc[4][4] = {};

  for (int k0 = 0; k0 < Ke; k0 += BK) {
    __syncthreads();  // prior iter's LDS reads done
    async_ld16(dstA0, ap0 + k0);
    async_ld16(dstA1, ap1 + k0);
    async_ld16(dstB0, bp0 + k0);
    async_ld16(dstB1, bp1 + k0);
    __syncthreads();  // compiler drains vmcnt before barrier

    short8 af[4], bfr[4];
#pragma unroll
    for (int i = 0; i < 4; i++)
      af[i] = As[q4 * 128 + wm * 64 + i * 16 + l15];
#pragma unroll
    for (int j = 0; j < 4; j++)
      bfr[j] = Bs[q4 * 128 + wn * 64 + j * 16 + l15];
#pragma unroll
    for (int i = 0; i < 4; i++)
#pragma unroll
      for (int j = 0; j < 4; j++)
        acc[i][j] = __builtin_amdgcn_mfma_f32_16x16x32_bf16(af[i], bfr[j], acc[i][j], 0, 0, 0);
  }

  // epilogue: C/D layout col=lane&15, row=(lane>>4)*4+reg  [m89/m91 verified]
#pragma unroll
  for (int i = 0; i < 4; i++) {
#pragma unroll
    for (int j = 0; j < 4; j++) {
#pragma unroll
      for (int r = 0; r < 4; r++) {
        const int row = bm0 + wm * 64 + i * 16 + q4 * 4 + r;
        const int col = bn0 + wn * 64 + j * 16 + l15;
        cstore(&Cz[(size_t)row * ldc + col], acc[i][j][r] * scale);
      }
    }
  }
}

// Single-pass register softmax over the causal prefix; one 256-thr block per
// (q,b) row of 2048. Reads 8 bf16/thread (16B), writes 8 bf16/thread.
// Zeros above the diagonal so the PV GEMM needs no masking.
__global__ __launch_bounds__(256)
void softmax_rows(const bf16* __restrict__ Sc, bf16* __restrict__ P, int S) {
  const int q = blockIdx.x, b = blockIdx.y;
  const short8* srow = (const short8*)(Sc + ((size_t)b * S + q) * S);
  short8* prow = (short8*)(P + ((size_t)b * S + q) * S);
  const int len = q + 1;
  const int tid = threadIdx.x;
  const int wave = tid >> 6, lane = tid & 63;
  __shared__ float red[10];

  const short8 raw = srow[tid];
  float v[8];
#pragma unroll
  for (int j = 0; j < 8; j++) {
    const int k = tid * 8 + j;
    const float f = __bfloat162float(((const bf16*)&raw)[j]);
    v[j] = (k < len) ? f : -1e30f;
  }

  float m = v[0];
#pragma unroll
  for (int j = 1; j < 8; j++) m = fmaxf(m, v[j]);
#pragma unroll
  for (int o = 32; o; o >>= 1) m = fmaxf(m, __shfl_down(m, o));
  if (lane == 0) red[wave] = m;
  __syncthreads();
  if (tid == 0) red[8] = fmaxf(fmaxf(red[0], red[1]), fmaxf(red[2], red[3]));
  __syncthreads();
  const float M = red[8];

  float e[8], s = 0.f;
#pragma unroll
  for (int j = 0; j < 8; j++) { e[j] = __expf(v[j] - M); s += e[j]; }
#pragma unroll
  for (int o = 32; o; o >>= 1) s += __shfl_down(s, o);
  if (lane == 0) red[4 + wave] = s;
  __syncthreads();
  if (tid == 0) red[9] = red[4] + red[5] + red[6] + red[7];
  __syncthreads();
  const float inv = 1.f / red[9];

  short8 outp;
#pragma unroll
  for (int j = 0; j < 8; j++) {
    const int k = tid * 8 + j;
    ((bf16*)&outp)[j] = __float2bfloat16((k < len) ? e[j] * inv : 0.f);
  }
  prow[tid] = outp;
}

extern "C" void kernel_launch(void* const* d_in, const int* in_sizes, int n_in,
                              void* d_out, int out_size, void* d_ws, size_t ws_size,
                              hipStream_t stream) {
  const float* x  = (const float*)d_in[0];
  const float* Wq = (const float*)d_in[1];
  const float* Wk = (const float*)d_in[2];
  const float* Wv = (const float*)d_in[3];
  float* out = (float*)d_out;

  const int Bb = 4, S = 2048, D = 1024, MS = Bb * S;  // MS = 8192

  // ws layout (bytes); P aliases the dead xb/W/Q region (all consumed
  // before softmax runs). Total ~102 MB.
  char* ws = (char*)d_ws;
  bf16* xb = (bf16*)ws;                                   // 16.78 MB
  bf16* wb = (bf16*)(ws + (size_t)MS * D * 2);            // Wq,Wk,Wv contig 6.3 MB
  bf16* Q  = (bf16*)(ws + (size_t)MS * D * 2 + 3u * D * D * 2);  // 16.78 MB
  bf16* Kp = Q + (size_t)MS * D;                          // 16.78 MB
  bf16* VT = Kp + (size_t)MS * D;                         // 16.78 MB, [D,MS] ld=MS
  bf16* Sc = VT + (size_t)MS * D;                         // 33.55 MB bf16 [B,S,S]
  bf16* P  = (bf16*)ws;                                   // aliases xb/W/Q

  dim3 blk(256);

  // downcast inputs to bf16
  f2b<<<dim3(MS * D / 4 / 256), blk, 0, stream>>>(x, xb, MS * D);
  f2b<<<dim3(D * D / 4 / 256), blk, 0, stream>>>(Wq, wb, D * D);
  f2b<<<dim3(D * D / 4 / 256), blk, 0, stream>>>(Wk, wb + (size_t)D * D, D * D);
  f2b<<<dim3(D * D / 4 / 256), blk, 0, stream>>>(Wv, wb + 2u * D * D, D * D);

  // [Q;K] = xb @ {Wq,Wk}^T  (z=2, contiguous weights & outputs)
  gemm_bt<bf16><<<dim3(D / BN, MS / BM, 2), blk, 0, stream>>>(
      xb, wb, Q, D, D, D, D, 0, (long)D * D, (long)MS * D, 1.f, 0, 0);
  // VT = Wv @ xb^T  [1024, 8192]
  gemm_bt<bf16><<<dim3(MS / BN, D / BM, 1), blk, 0, stream>>>(
      wb + 2u * D * D, xb, VT, D, D, MS, D, 0, 0, 0, 1.f, 0, 0);
  // Sc = (Q K^T)/32 per batch, lower-triangular tiles only (bf16 out)
  gemm_bt<bf16><<<dim3(S / BN, S / BM, Bb), blk, 0, stream>>>(
      Q, Kp, Sc, D, D, S, D,
      (long)S * D, (long)S * D, (long)S * S, 0.03125f, 1, 0);
  // P = row-softmax(Sc), zero above diagonal
  softmax_rows<<<dim3(S, Bb), blk, 0, stream>>>(Sc, P, S);
  // out = P @ V (B-operand = VT batch slice, K clipped at diagonal), fp32 out
  gemm_bt<float><<<dim3(D / BN, S / BM, Bb), blk, 0, stream>>>(
      P, VT, out, S, MS, D, S,
      (long)S * S, (long)S, (long)S * D, 1.f, 0, 1);
}

// Round 3
// 356.707 us; speedup vs baseline: 1.0210x; 1.0210x over previous
//
#include <hip/hip_runtime.h>
#include <hip/hip_bf16.h>
#include <stdint.h>
#include <stddef.h>

// Causal single-head attention, B=4 S=2048 D=1024. fp32 in/out; bf16 MFMA inside.
// Pipeline: downcast x,W* -> bf16 ; [Q;K] = x W^T (z=2) ; VT = Wv x^T ;
// Sc = Q K^T / 32 (bf16, causal tile skip) ; P = row-softmax(Sc) (bf16) ;
// out = P V (fp32 epilogue, K clipped at diagonal, reversed by for tail).
// R2: BK=64 (32 MFMA per barrier-drain instead of 16) — latency-bound fix.

typedef __hip_bfloat16 bf16;
typedef short short8 __attribute__((ext_vector_type(8)));
typedef short short4v __attribute__((ext_vector_type(4)));
typedef float f32x4 __attribute__((ext_vector_type(4)));

#define BM 128
#define BN 128
#define BK 64

__device__ __forceinline__ void async_ld16(void* lds, const void* g) {
  __builtin_amdgcn_global_load_lds(
      (const __attribute__((address_space(1))) unsigned int*)g,
      (__attribute__((address_space(3))) unsigned int*)lds, 16, 0, 0);
}

__device__ __forceinline__ void cstore(float* p, float v) { *p = v; }
__device__ __forceinline__ void cstore(bf16* p, float v) { *p = __float2bfloat16(v); }

// fp32 -> bf16 downcast, 4 elems/thread
__global__ __launch_bounds__(256)
void f2b(const float* __restrict__ s, bf16* __restrict__ d, int n) {
  const int i = (blockIdx.x * 256 + threadIdx.x) * 4;
  if (i >= n) return;
  const float4 v = *(const float4*)(s + i);
  bf16 t[4] = {__float2bfloat16(v.x), __float2bfloat16(v.y),
               __float2bfloat16(v.z), __float2bfloat16(v.w)};
  *(short4v*)(d + i) = *(short4v*)t;
}

// three weight matrices -> contiguous bf16 block, one dispatch
__global__ __launch_bounds__(256)
void f2b3(const float* __restrict__ a, const float* __restrict__ b,
          const float* __restrict__ c, bf16* __restrict__ d, int n) {
  const float* s = (blockIdx.y == 0) ? a : (blockIdx.y == 1) ? b : c;
  const int i = (blockIdx.x * 256 + threadIdx.x) * 4;
  if (i >= n) return;
  const float4 v = *(const float4*)(s + i);
  bf16 t[4] = {__float2bfloat16(v.x), __float2bfloat16(v.y),
               __float2bfloat16(v.z), __float2bfloat16(v.w)};
  *(short4v*)(d + (size_t)blockIdx.y * n + i) = *(short4v*)t;
}

// C[M,N] = A[M,K] * B[N,K]^T (both K-contiguous), bf16 in, CT out.
// BK=64: LDS As/Bs hold 8 k-chunks of 8 bf16 x 128 rows (16 KB each).
// Wave w stages chunks 2w,2w+1; ds_read_b128 fragments are bank-uniform.
template <typename CT>
__global__ __launch_bounds__(256, 3)
void gemm_bt(const bf16* __restrict__ A, const bf16* __restrict__ B,
             CT* __restrict__ C, int lda, int ldb, int ldc, int K,
             long sA, long sB, long sC, float scale,
             int causal_skip, int causal_klimit) {
  int by = blockIdx.y, bx = blockIdx.x;
  if (causal_klimit) by = gridDim.y - 1 - by;  // long-K blocks dispatch first
  if (causal_skip && bx > by) return;          // tile fully above diagonal

  __shared__ short8 As[8 * 128];  // 16 KB
  __shared__ short8 Bs[8 * 128];  // 16 KB

  const int tid = threadIdx.x;
  const int wave = tid >> 6, lane = tid & 63;
  const int wm = wave >> 1, wn = wave & 1;  // 2x2 wave grid, 64x64 each
  const int l15 = lane & 15, q4 = lane >> 4;
  const int bm0 = by * BM, bn0 = bx * BN;

  const bf16* Az = A + (long)blockIdx.z * sA;
  const bf16* Bz = B + (long)blockIdx.z * sB;
  CT* Cz = C + (long)blockIdx.z * sC;

  // wave w stages k-chunks c=2w,2w+1 (8 bf16 each) for rows {lane, lane+64}
  const int c0 = 2 * wave;
  const bf16* a00 = Az + (size_t)(bm0 + lane) * lda + c0 * 8;
  const bf16* a01 = a00 + (size_t)64 * lda;
  const bf16* a10 = a00 + 8;
  const bf16* a11 = a01 + 8;
  const bf16* b00 = Bz + (size_t)(bn0 + lane) * ldb + c0 * 8;
  const bf16* b01 = b00 + (size_t)64 * ldb;
  const bf16* b10 = b00 + 8;
  const bf16* b11 = b01 + 8;
  short8* dA00 = &As[c0 * 128 + lane];
  short8* dA01 = &As[c0 * 128 + 64 + lane];
  short8* dA10 = &As[(c0 + 1) * 128 + lane];
  short8* dA11 = &As[(c0 + 1) * 128 + 64 + lane];
  short8* dB00 = &Bs[c0 * 128 + lane];
  short8* dB01 = &Bs[c0 * 128 + 64 + lane];
  short8* dB10 = &Bs[(c0 + 1) * 128 + lane];
  short8* dB11 = &Bs[(c0 + 1) * 128 + 64 + lane];

  const int Ke = causal_klimit ? min(K, (by + 1) * BM) : K;

  f32x4 acc[4][4] = {};

  for (int k0 = 0; k0 < Ke; k0 += BK) {
    __syncthreads();  // prior iter's LDS reads done
    async_ld16(dA00, a00 + k0);
    async_ld16(dA01, a01 + k0);
    async_ld16(dA10, a10 + k0);
    async_ld16(dA11, a11 + k0);
    async_ld16(dB00, b00 + k0);
    async_ld16(dB01, b01 + k0);
    async_ld16(dB10, b10 + k0);
    async_ld16(dB11, b11 + k0);
    __syncthreads();  // compiler drains vmcnt before barrier

#pragma unroll
    for (int s = 0; s < 2; s++) {
      short8 af[4], bfr[4];
#pragma unroll
      for (int i = 0; i < 4; i++)
        af[i] = As[(s * 4 + q4) * 128 + wm * 64 + i * 16 + l15];
#pragma unroll
      for (int j = 0; j < 4; j++)
        bfr[j] = Bs[(s * 4 + q4) * 128 + wn * 64 + j * 16 + l15];
#pragma unroll
      for (int i = 0; i < 4; i++)
#pragma unroll
        for (int j = 0; j < 4; j++)
          acc[i][j] = __builtin_amdgcn_mfma_f32_16x16x32_bf16(af[i], bfr[j], acc[i][j], 0, 0, 0);
    }
  }

  // epilogue: C/D layout col=lane&15, row=(lane>>4)*4+reg  [m89/m91 verified]
#pragma unroll
  for (int i = 0; i < 4; i++) {
#pragma unroll
    for (int j = 0; j < 4; j++) {
#pragma unroll
      for (int r = 0; r < 4; r++) {
        const int row = bm0 + wm * 64 + i * 16 + q4 * 4 + r;
        const int col = bn0 + wn * 64 + j * 16 + l15;
        cstore(&Cz[(size_t)row * ldc + col], acc[i][j][r] * scale);
      }
    }
  }
}

// Single-pass register softmax over the causal prefix; one 256-thr block per
// (q,b) row. Zeros above the diagonal so the PV GEMM needs no masking.
__global__ __launch_bounds__(256)
void softmax_rows(const bf16* __restrict__ Sc, bf16* __restrict__ P, int S) {
  const int q = blockIdx.x, b = blockIdx.y;
  const short8* srow = (const short8*)(Sc + ((size_t)b * S + q) * S);
  short8* prow = (short8*)(P + ((size_t)b * S + q) * S);
  const int len = q + 1;
  const int tid = threadIdx.x;
  const int wave = tid >> 6, lane = tid & 63;
  __shared__ float red[10];

  const short8 raw = srow[tid];
  float v[8];
#pragma unroll
  for (int j = 0; j < 8; j++) {
    const int k = tid * 8 + j;
    const float f = __bfloat162float(((const bf16*)&raw)[j]);
    v[j] = (k < len) ? f : -1e30f;
  }

  float m = v[0];
#pragma unroll
  for (int j = 1; j < 8; j++) m = fmaxf(m, v[j]);
#pragma unroll
  for (int o = 32; o; o >>= 1) m = fmaxf(m, __shfl_down(m, o));
  if (lane == 0) red[wave] = m;
  __syncthreads();
  if (tid == 0) red[8] = fmaxf(fmaxf(red[0], red[1]), fmaxf(red[2], red[3]));
  __syncthreads();
  const float M = red[8];

  float e[8], s = 0.f;
#pragma unroll
  for (int j = 0; j < 8; j++) { e[j] = __expf(v[j] - M); s += e[j]; }
#pragma unroll
  for (int o = 32; o; o >>= 1) s += __shfl_down(s, o);
  if (lane == 0) red[4 + wave] = s;
  __syncthreads();
  if (tid == 0) red[9] = red[4] + red[5] + red[6] + red[7];
  __syncthreads();
  const float inv = 1.f / red[9];

  short8 outp;
#pragma unroll
  for (int j = 0; j < 8; j++) {
    const int k = tid * 8 + j;
    ((bf16*)&outp)[j] = __float2bfloat16((k < len) ? e[j] * inv : 0.f);
  }
  prow[tid] = outp;
}

extern "C" void kernel_launch(void* const* d_in, const int* in_sizes, int n_in,
                              void* d_out, int out_size, void* d_ws, size_t ws_size,
                              hipStream_t stream) {
  const float* x  = (const float*)d_in[0];
  const float* Wq = (const float*)d_in[1];
  const float* Wk = (const float*)d_in[2];
  const float* Wv = (const float*)d_in[3];
  float* out = (float*)d_out;

  const int Bb = 4, S = 2048, D = 1024, MS = Bb * S;  // MS = 8192

  // ws layout; P aliases dead xb/W/Q region (consumed before softmax).
  char* ws = (char*)d_ws;
  bf16* xb = (bf16*)ws;                                          // 16.78 MB
  bf16* wb = (bf16*)(ws + (size_t)MS * D * 2);                   // 6.3 MB
  bf16* Q  = (bf16*)(ws + (size_t)MS * D * 2 + 3u * D * D * 2);  // 16.78 MB
  bf16* Kp = Q + (size_t)MS * D;                                 // 16.78 MB
  bf16* VT = Kp + (size_t)MS * D;                                // 16.78 MB [D,MS]
  bf16* Sc = VT + (size_t)MS * D;                                // 33.55 MB [B,S,S]
  bf16* P  = (bf16*)ws;                                          // aliases xb/W/Q

  dim3 blk(256);

  f2b<<<dim3(MS * D / 4 / 256), blk, 0, stream>>>(x, xb, MS * D);
  f2b3<<<dim3(D * D / 4 / 256, 3), blk, 0, stream>>>(Wq, Wk, Wv, wb, D * D);

  // [Q;K] = xb @ {Wq,Wk}^T  (z=2)
  gemm_bt<bf16><<<dim3(D / BN, MS / BM, 2), blk, 0, stream>>>(
      xb, wb, Q, D, D, D, D, 0, (long)D * D, (long)MS * D, 1.f, 0, 0);
  // VT = Wv @ xb^T  [1024, 8192]
  gemm_bt<bf16><<<dim3(MS / BN, D / BM, 1), blk, 0, stream>>>(
      wb + 2u * D * D, xb, VT, D, D, MS, D, 0, 0, 0, 1.f, 0, 0);
  // Sc = (Q K^T)/32 per batch, lower-triangular tiles only
  gemm_bt<bf16><<<dim3(S / BN, S / BM, Bb), blk, 0, stream>>>(
      Q, Kp, Sc, D, D, S, D,
      (long)S * D, (long)S * D, (long)S * S, 0.03125f, 1, 0);
  // P = row-softmax(Sc)
  softmax_rows<<<dim3(S, Bb), blk, 0, stream>>>(Sc, P, S);
  // out = P @ V  (B = VT batch slice, K clipped at diagonal)
  gemm_bt<float><<<dim3(D / BN, S / BM, Bb), blk, 0, stream>>>(
      P, VT, out, S, MS, D, S,
      (long)S * S, (long)S, (long)S * D, 1.f, 0, 1);
}